// Round 6
// baseline (570.197 us; speedup 1.0000x reference)
//
#include <hip/hip_runtime.h>

#define NN 100000
#define NE 800000
#define HD 64
#define BK 128                            // nodes per bucket
#define NBUCK ((NN + BK - 1) / BK)        // 782
#define PA_EPT 16                         // edges per thread in passA
#define PA_NB ((NE + 256 * PA_EPT - 1) / (256 * PA_EPT))   // 196
#define LDW 68                            // padded leading dim (bank rotate)

__device__ __forceinline__ int load_idx(const void* ei, int i, bool is32) {
    if (is32) return ((const int*)ei)[i];
    return (int)(((const long long*)ei)[i]);
}

// zero flag + bucket counters
__global__ void k_init(int* bcnt, int* flag) {
    int t = threadIdx.x;
    if (t < NBUCK) bcnt[t] = 0;
    if (t == NBUCK) *flag = 0;
}

// detect int32 vs int64: one block checks the first 4096 int64 slots.
__global__ void k_detect(const void* ei, int* flag) {
    __shared__ int bad;
    if (threadIdx.x == 0) bad = 0;
    __syncthreads();
    const long long* p = (const long long*)ei;
    for (int i = threadIdx.x; i < 4096; i += 1024) {
        long long v = p[i];
        if (v < 0 || v >= (long long)NN) bad = 1;
    }
    __syncthreads();
    if (threadIdx.x == 0 && bad) *flag = 1;
}

// global bucket histogram via per-block LDS histograms
__global__ __launch_bounds__(256) void k_pass0(const void* ei, const int* flag,
                                               int* bcnt) {
    __shared__ int h[NBUCK];
    for (int i = threadIdx.x; i < NBUCK; i += 256) h[i] = 0;
    __syncthreads();
    bool is32 = (*flag != 0);
    int stride = gridDim.x * 256;
    for (int e = blockIdx.x * 256 + threadIdx.x; e < NE; e += stride) {
        int dst = load_idx(ei, NE + e, is32);
        atomicAdd(&h[dst >> 7], 1);
    }
    __syncthreads();
    for (int i = threadIdx.x; i < NBUCK; i += 256) {
        int v = h[i];
        if (v) atomicAdd(&bcnt[i], v);
    }
}

// scan 782 bucket counts -> offs[0..NBUCK], curs[b]=offs[b]
__global__ __launch_bounds__(256) void k_scan1(const int* __restrict__ bcnt,
                                               int* __restrict__ offs,
                                               int* __restrict__ curs) {
    __shared__ int sc[256];
    int t = threadIdx.x;
    int v[4], s = 0;
#pragma unroll
    for (int i = 0; i < 4; ++i) {
        int b = t * 4 + i;
        v[i] = (b < NBUCK) ? bcnt[b] : 0;
        s += v[i];
    }
    sc[t] = s;
    __syncthreads();
    for (int off = 1; off < 256; off <<= 1) {
        int add = (t >= off) ? sc[t - off] : 0;
        __syncthreads();
        sc[t] += add;
        __syncthreads();
    }
    int run = sc[t] - s;   // exclusive prefix
#pragma unroll
    for (int i = 0; i < 4; ++i) {
        int b = t * 4 + i;
        if (b < NBUCK) { offs[b] = run; curs[b] = run; }
        run += v[i];
    }
    if (t == 255) offs[NBUCK] = sc[255];
}

// bin edges into bucket-major ebuf; packed word = src | (dst&127)<<17
__global__ __launch_bounds__(256) void k_passA(const void* ei, const int* flag,
                                               int* curs, unsigned* ebuf) {
    __shared__ int h[NBUCK];
    __shared__ int base[NBUCK];
    for (int i = threadIdx.x; i < NBUCK; i += 256) h[i] = 0;
    __syncthreads();
    bool is32 = (*flag != 0);
    int e0 = blockIdx.x * (256 * PA_EPT);
    int src[PA_EPT], dst[PA_EPT];
#pragma unroll
    for (int i = 0; i < PA_EPT; ++i) {
        int e = e0 + i * 256 + threadIdx.x;
        if (e < NE) {
            src[i] = load_idx(ei, e, is32);
            dst[i] = load_idx(ei, NE + e, is32);
            atomicAdd(&h[dst[i] >> 7], 1);
        } else dst[i] = -1;
    }
    __syncthreads();
    for (int i = threadIdx.x; i < NBUCK; i += 256) {
        int v = h[i];
        base[i] = v ? atomicAdd(&curs[i], v) : 0;
        h[i] = 0;                      // reuse as local rank counter
    }
    __syncthreads();
#pragma unroll
    for (int i = 0; i < PA_EPT; ++i) {
        if (dst[i] >= 0) {
            int b = dst[i] >> 7;
            int p = base[b] + atomicAdd(&h[b], 1);
            ebuf[p] = (unsigned)src[i] | ((unsigned)(dst[i] & 127) << 17);
        }
    }
}

// per-bucket counting sort -> per-node CSR (noffs, csr_src) + dinv.
__global__ __launch_bounds__(256) void k_passB(const unsigned* __restrict__ ebuf,
                                               const int* __restrict__ offs,
                                               int* __restrict__ noffs,
                                               int* __restrict__ csr_src,
                                               float* __restrict__ dinv) {
    __shared__ int cnt[BK];
    __shared__ int sc[BK];
    __shared__ int nbase[BK];
    __shared__ int rank[BK];
    int bk = blockIdx.x;
    int t = threadIdx.x;
    if (t < BK) { cnt[t] = 0; rank[t] = 0; }
    __syncthreads();
    int rs = offs[bk], re = offs[bk + 1];
    for (int i = rs + t; i < re; i += 256)
        atomicAdd(&cnt[ebuf[i] >> 17], 1);
    __syncthreads();
    if (t < BK) sc[t] = cnt[t];
    __syncthreads();
    for (int off = 1; off < BK; off <<= 1) {       // inclusive scan of cnt
        int v = 0;
        if (t < BK && t >= off) v = sc[t - off];
        __syncthreads();
        if (t < BK) sc[t] += v;
        __syncthreads();
    }
    if (t < BK) {
        int node = bk * BK + t;
        int nb = rs + sc[t] - cnt[t];              // exclusive prefix
        nbase[t] = nb;
        if (node < NN) {
            noffs[node] = nb;
            dinv[node] = rsqrtf((float)(cnt[t] + 1));
        }
    }
    if (bk == NBUCK - 1 && t == 0) noffs[NN] = re;
    __syncthreads();
    for (int i = rs + t; i < re; i += 256) {
        unsigned w = ebuf[i];
        int dl = w >> 17;
        int p = nbase[dl] + atomicAdd(&rank[dl], 1);
        csr_src[p] = (int)(w & 0x1FFFFu);
    }
}

// H[n x 64] = X[n x 64] @ W[64 x 64]; 4x4 register blocking, k-unroll 4,
// ds_read_b128 everywhere (8 LDS instrs per 64 FMAs). 64 rows per block.
// Optional bias; optional row-prescale by dinv (Hs = dinv[r] * (X@W)[r]).
template <bool BIAS, bool PRE>
__global__ __launch_bounds__(256) void k_gemm(const float* __restrict__ X,
                                              const float* __restrict__ W,
                                              const float* __restrict__ bias,
                                              const float* __restrict__ dinv,
                                              float* __restrict__ H, int n) {
    __shared__ float Ws[64 * LDW];
    __shared__ float Xs[64 * LDW];
    int t = threadIdx.x;
    int row0 = blockIdx.x * 64;
    for (int i = t; i < 64 * 64; i += 256)
        Ws[(i >> 6) * LDW + (i & 63)] = W[i];
    for (int i = t; i < 64 * 64; i += 256) {
        int r = row0 + (i >> 6);
        Xs[(i >> 6) * LDW + (i & 63)] = (r < n) ? X[(size_t)r * 64 + (i & 63)] : 0.f;
    }
    __syncthreads();
    int tc = (t & 15) * 4;       // 4 output cols
    int tr = (t >> 4) * 4;       // 4 output rows
    float acc[4][4] = {};
    for (int k = 0; k < 64; k += 4) {
        float4 wv[4], xv[4];
#pragma unroll
        for (int kk = 0; kk < 4; ++kk)
            wv[kk] = *(const float4*)&Ws[(k + kk) * LDW + tc];
#pragma unroll
        for (int rr = 0; rr < 4; ++rr)
            xv[rr] = *(const float4*)&Xs[(tr + rr) * LDW + k];
#pragma unroll
        for (int rr = 0; rr < 4; ++rr) {
            acc[rr][0] += xv[rr].x * wv[0].x + xv[rr].y * wv[1].x
                        + xv[rr].z * wv[2].x + xv[rr].w * wv[3].x;
            acc[rr][1] += xv[rr].x * wv[0].y + xv[rr].y * wv[1].y
                        + xv[rr].z * wv[2].y + xv[rr].w * wv[3].y;
            acc[rr][2] += xv[rr].x * wv[0].z + xv[rr].y * wv[1].z
                        + xv[rr].z * wv[2].z + xv[rr].w * wv[3].z;
            acc[rr][3] += xv[rr].x * wv[0].w + xv[rr].y * wv[1].w
                        + xv[rr].z * wv[2].w + xv[rr].w * wv[3].w;
        }
    }
    float4 bv = make_float4(0.f, 0.f, 0.f, 0.f);
    if (BIAS) bv = *(const float4*)&bias[tc];
#pragma unroll
    for (int rr = 0; rr < 4; ++rr) {
        int r = row0 + tr + rr;
        if (r < n) {
            float s = PRE ? dinv[r] : 1.f;
            float4 o;
            o.x = (acc[rr][0] + bv.x) * s;
            o.y = (acc[rr][1] + bv.y) * s;
            o.z = (acc[rr][2] + bv.z) * s;
            o.w = (acc[rr][3] + bv.w) * s;
            *(float4*)&H[(size_t)r * 64 + tc] = o;
        }
    }
}

// Aggregation: wave = 1 node; 4 groups of 16 lanes; group g walks edges
// e0+g, e0+g+4, ... loading prescaled rows as float4; 8 rows in flight/wave.
// out[n] = relu( dinv[n]*(sum_e Hs[src] + Hs[n]) + b )
__global__ __launch_bounds__(256) void k_agg(const float4* __restrict__ Hs4,
                                             const int* __restrict__ noffs,
                                             const int* __restrict__ csr_src,
                                             const float* __restrict__ dinv,
                                             const float4* __restrict__ b4,
                                             float4* __restrict__ out4) {
    int node = blockIdx.x * 4 + (threadIdx.x >> 6);
    if (node >= NN) return;
    int lane = threadIdx.x & 63;
    int g = lane >> 4;          // edge group 0..3
    int q = lane & 15;          // float4 chunk within the 64-feature row
    float dv = dinv[node];

    float4 acc = make_float4(0.f, 0.f, 0.f, 0.f);
    if (g == 0) acc = Hs4[(size_t)node * 16 + q];   // self-loop (prescaled)
    int e0 = noffs[node], e1 = noffs[node + 1];
    int e = e0 + g;
    for (; e + 4 < e1; e += 8) {
        int s0 = csr_src[e], s1 = csr_src[e + 4];
        float4 h0 = Hs4[(size_t)s0 * 16 + q];
        float4 h1 = Hs4[(size_t)s1 * 16 + q];
        acc.x += h0.x + h1.x; acc.y += h0.y + h1.y;
        acc.z += h0.z + h1.z; acc.w += h0.w + h1.w;
    }
    if (e < e1) {
        int s = csr_src[e];
        float4 h = Hs4[(size_t)s * 16 + q];
        acc.x += h.x; acc.y += h.y; acc.z += h.z; acc.w += h.w;
    }
#pragma unroll
    for (int off = 16; off < 64; off <<= 1) {
        acc.x += __shfl_xor(acc.x, off, 64);
        acc.y += __shfl_xor(acc.y, off, 64);
        acc.z += __shfl_xor(acc.z, off, 64);
        acc.w += __shfl_xor(acc.w, off, 64);
    }
    if (g == 0) {
        float4 bv = b4[q];
        float4 r;
        r.x = fmaxf(acc.x * dv + bv.x, 0.f);
        r.y = fmaxf(acc.y * dv + bv.y, 0.f);
        r.z = fmaxf(acc.z * dv + bv.z, 0.f);
        r.w = fmaxf(acc.w * dv + bv.w, 0.f);
        out4[(size_t)node * 16 + q] = r;
    }
}

extern "C" void kernel_launch(void* const* d_in, const int* in_sizes, int n_in,
                              void* d_out, int out_size, void* d_ws, size_t ws_size,
                              hipStream_t stream) {
    const float* x  = (const float*)d_in[0];
    const void*  ei = d_in[1];               // edge_index, dtype detected on device
    const float* W0 = (const float*)d_in[3];
    const float* b0 = (const float*)d_in[4];
    const float* W1 = (const float*)d_in[5];
    const float* b1 = (const float*)d_in[6];
    const float* W2 = (const float*)d_in[7];
    const float* b2 = (const float*)d_in[8];
    const float* Wl = (const float*)d_in[9];
    const float* bl = (const float*)d_in[10];

    char* ws = (char*)d_ws;
    int*      flag    = (int*)(ws);
    int*      bcnt    = (int*)(ws + 256);
    int*      offs    = (int*)(ws + 4352);        // 783 ints
    int*      curs    = (int*)(ws + 8448);        // 782 ints
    float*    dinv    = (float*)(ws + 12544);     // 400000 B
    int*      noffs   = (int*)(ws + 412672);      // 100001 ints
    int*      csr_src = (int*)(ws + 812800);      // 3.2 MB

    float* out0 = (float*)d_out;             // first output (layer-3 relu)
    float* out1 = out0 + (size_t)NN * HD;    // second output; Hs scratch
    unsigned* ebuf = (unsigned*)out1;        // bucket-major edges; dies before GEMM0

    int gG = (NN + 63) / 64;                 // 1563 gemm blocks
    int gA = (NN + 3) / 4;                   // 25000 agg blocks

    // ---- preprocessing: bucket bin + in-bucket counting sort -> CSR ----
    k_init<<<1, 1024, 0, stream>>>(bcnt, flag);
    k_detect<<<1, 1024, 0, stream>>>(ei, flag);
    k_pass0<<<128, 256, 0, stream>>>(ei, flag, bcnt);
    k_scan1<<<1, 256, 0, stream>>>(bcnt, offs, curs);
    k_passA<<<PA_NB, 256, 0, stream>>>(ei, flag, curs, ebuf);
    k_passB<<<NBUCK, 256, 0, stream>>>(ebuf, offs, noffs, csr_src, dinv);

    // ---- layer 0 ----
    k_gemm<false, true><<<gG, 256, 0, stream>>>(x, W0, nullptr, dinv, out1, NN);
    k_agg<<<gA, 256, 0, stream>>>((const float4*)out1, noffs, csr_src, dinv,
                                  (const float4*)b0, (float4*)out0);
    // ---- layer 1 ----
    k_gemm<false, true><<<gG, 256, 0, stream>>>(out0, W1, nullptr, dinv, out1, NN);
    k_agg<<<gA, 256, 0, stream>>>((const float4*)out1, noffs, csr_src, dinv,
                                  (const float4*)b1, (float4*)out0);
    // ---- layer 2 ----
    k_gemm<false, true><<<gG, 256, 0, stream>>>(out0, W2, nullptr, dinv, out1, NN);
    k_agg<<<gA, 256, 0, stream>>>((const float4*)out1, noffs, csr_src, dinv,
                                  (const float4*)b2, (float4*)out0);
    // ---- final linear ----
    k_gemm<true, false><<<gG, 256, 0, stream>>>(out0, Wl, bl, nullptr, out1, NN);
}

// Round 7
// 349.693 us; speedup vs baseline: 1.6306x; 1.6306x over previous
//
#include <hip/hip_runtime.h>

#define NN 100000
#define NE 800000
#define HD 64
#define BK 128                            // nodes per bucket
#define NBUCK ((NN + BK - 1) / BK)        // 782
#define PA_EPT 16                         // edges per thread in passA
#define PA_NB ((NE + 256 * PA_EPT - 1) / (256 * PA_EPT))   // 196
#define LDW 68                            // padded leading dim: 68 f = 272 B = 17*16 B
                                          // (b128-aligned rows, +4 bank rotate/row)

__device__ __forceinline__ int load_idx(const void* ei, int i, bool is32) {
    if (is32) return ((const int*)ei)[i];
    return (int)(((const long long*)ei)[i]);
}

// zero flag + bucket counters
__global__ void k_init(int* bcnt, int* flag) {
    int t = threadIdx.x;
    if (t < NBUCK) bcnt[t] = 0;
    if (t == NBUCK) *flag = 0;
}

// detect int32 vs int64: one block checks the first 4096 int64 slots.
__global__ void k_detect(const void* ei, int* flag) {
    __shared__ int bad;
    if (threadIdx.x == 0) bad = 0;
    __syncthreads();
    const long long* p = (const long long*)ei;
    for (int i = threadIdx.x; i < 4096; i += 1024) {
        long long v = p[i];
        if (v < 0 || v >= (long long)NN) bad = 1;
    }
    __syncthreads();
    if (threadIdx.x == 0 && bad) *flag = 1;
}

// global bucket histogram via per-block LDS histograms
__global__ __launch_bounds__(256) void k_pass0(const void* ei, const int* flag,
                                               int* bcnt) {
    __shared__ int h[NBUCK];
    for (int i = threadIdx.x; i < NBUCK; i += 256) h[i] = 0;
    __syncthreads();
    bool is32 = (*flag != 0);
    int stride = gridDim.x * 256;
    for (int e = blockIdx.x * 256 + threadIdx.x; e < NE; e += stride) {
        int dst = load_idx(ei, NE + e, is32);
        atomicAdd(&h[dst >> 7], 1);
    }
    __syncthreads();
    for (int i = threadIdx.x; i < NBUCK; i += 256) {
        int v = h[i];
        if (v) atomicAdd(&bcnt[i], v);
    }
}

// scan 782 bucket counts -> offs[0..NBUCK], curs[b]=offs[b]
__global__ __launch_bounds__(256) void k_scan1(const int* __restrict__ bcnt,
                                               int* __restrict__ offs,
                                               int* __restrict__ curs) {
    __shared__ int sc[256];
    int t = threadIdx.x;
    int v[4], s = 0;
#pragma unroll
    for (int i = 0; i < 4; ++i) {
        int b = t * 4 + i;
        v[i] = (b < NBUCK) ? bcnt[b] : 0;
        s += v[i];
    }
    sc[t] = s;
    __syncthreads();
    for (int off = 1; off < 256; off <<= 1) {
        int add = (t >= off) ? sc[t - off] : 0;
        __syncthreads();
        sc[t] += add;
        __syncthreads();
    }
    int run = sc[t] - s;   // exclusive prefix
#pragma unroll
    for (int i = 0; i < 4; ++i) {
        int b = t * 4 + i;
        if (b < NBUCK) { offs[b] = run; curs[b] = run; }
        run += v[i];
    }
    if (t == 255) offs[NBUCK] = sc[255];
}

// bin edges into bucket-major ebuf; packed word = src | (dst&127)<<17
__global__ __launch_bounds__(256) void k_passA(const void* ei, const int* flag,
                                               int* curs, unsigned* ebuf) {
    __shared__ int h[NBUCK];
    __shared__ int base[NBUCK];
    for (int i = threadIdx.x; i < NBUCK; i += 256) h[i] = 0;
    __syncthreads();
    bool is32 = (*flag != 0);
    int e0 = blockIdx.x * (256 * PA_EPT);
    int src[PA_EPT], dst[PA_EPT];
#pragma unroll
    for (int i = 0; i < PA_EPT; ++i) {
        int e = e0 + i * 256 + threadIdx.x;
        if (e < NE) {
            src[i] = load_idx(ei, e, is32);
            dst[i] = load_idx(ei, NE + e, is32);
            atomicAdd(&h[dst[i] >> 7], 1);
        } else dst[i] = -1;
    }
    __syncthreads();
    for (int i = threadIdx.x; i < NBUCK; i += 256) {
        int v = h[i];
        base[i] = v ? atomicAdd(&curs[i], v) : 0;
        h[i] = 0;                      // reuse as local rank counter
    }
    __syncthreads();
#pragma unroll
    for (int i = 0; i < PA_EPT; ++i) {
        if (dst[i] >= 0) {
            int b = dst[i] >> 7;
            int p = base[b] + atomicAdd(&h[b], 1);
            ebuf[p] = (unsigned)src[i] | ((unsigned)(dst[i] & 127) << 17);
        }
    }
}

// per-bucket counting sort -> per-node CSR (noffs, csr_src) + dinv.
__global__ __launch_bounds__(256) void k_passB(const unsigned* __restrict__ ebuf,
                                               const int* __restrict__ offs,
                                               int* __restrict__ noffs,
                                               int* __restrict__ csr_src,
                                               float* __restrict__ dinv) {
    __shared__ int cnt[BK];
    __shared__ int sc[BK];
    __shared__ int nbase[BK];
    __shared__ int rank[BK];
    int bk = blockIdx.x;
    int t = threadIdx.x;
    if (t < BK) { cnt[t] = 0; rank[t] = 0; }
    __syncthreads();
    int rs = offs[bk], re = offs[bk + 1];
    for (int i = rs + t; i < re; i += 256)
        atomicAdd(&cnt[ebuf[i] >> 17], 1);
    __syncthreads();
    if (t < BK) sc[t] = cnt[t];
    __syncthreads();
    for (int off = 1; off < BK; off <<= 1) {       // inclusive scan of cnt
        int v = 0;
        if (t < BK && t >= off) v = sc[t - off];
        __syncthreads();
        if (t < BK) sc[t] += v;
        __syncthreads();
    }
    if (t < BK) {
        int node = bk * BK + t;
        int nb = rs + sc[t] - cnt[t];              // exclusive prefix
        nbase[t] = nb;
        if (node < NN) {
            noffs[node] = nb;
            dinv[node] = rsqrtf((float)(cnt[t] + 1));
        }
    }
    if (bk == NBUCK - 1 && t == 0) noffs[NN] = re;
    __syncthreads();
    for (int i = rs + t; i < re; i += 256) {
        unsigned w = ebuf[i];
        int dl = w >> 17;
        int p = nbase[dl] + atomicAdd(&rank[dl], 1);
        csr_src[p] = (int)(w & 0x1FFFFu);
    }
}

// H[n x 64] = X[n x 64] @ W[64 x 64]; 128 rows/block; thread = 8 rows
// (strided by 16: bank-conflict-free) x 4 cols. k-loop NOT unrolled
// (#pragma unroll 1) + __launch_bounds__(256,4) to cap VGPR at 128 —
// R6's full unroll hit the 256-VGPR cap and collapsed occupancy.
// Per 4 k-steps: 12 ds_read_b128 feed 128 FMAs (VALU-bound by design).
template <bool BIAS, bool PRE>
__global__ __launch_bounds__(256, 4) void k_gemm(const float* __restrict__ X,
                                                 const float* __restrict__ W,
                                                 const float* __restrict__ bias,
                                                 const float* __restrict__ dinv,
                                                 float* __restrict__ H, int n) {
    __shared__ float Ws[64 * LDW];     // 17.4 KB
    __shared__ float Xs[128 * LDW];    // 34.8 KB
    int t = threadIdx.x;
    int row0 = blockIdx.x * 128;
    const float4* X4 = (const float4*)X;
    for (int i = t; i < 64 * 16; i += 256) {       // W: 1024 float4
        float4 v = ((const float4*)W)[i];
        *(float4*)&Ws[(i >> 4) * LDW + (i & 15) * 4] = v;
    }
    for (int i = t; i < 128 * 16; i += 256) {      // X tile: 2048 float4
        int r = row0 + (i >> 4);
        float4 v = (r < n) ? X4[(size_t)r * 16 + (i & 15)]
                           : make_float4(0.f, 0.f, 0.f, 0.f);
        *(float4*)&Xs[(i >> 4) * LDW + (i & 15) * 4] = v;
    }
    __syncthreads();
    int tc = (t & 15) * 4;       // 4 output cols
    int rbase = t >> 4;          // rows rbase + 16*i, i=0..7
    float4 acc[8] = {};
#pragma unroll 1
    for (int k = 0; k < 64; k += 4) {
        float4 wv[4], xv[8];
#pragma unroll
        for (int kk = 0; kk < 4; ++kk)
            wv[kk] = *(const float4*)&Ws[(k + kk) * LDW + tc];
#pragma unroll
        for (int i = 0; i < 8; ++i)
            xv[i] = *(const float4*)&Xs[(rbase + 16 * i) * LDW + k];
#pragma unroll
        for (int i = 0; i < 8; ++i) {
            acc[i].x += xv[i].x * wv[0].x + xv[i].y * wv[1].x
                      + xv[i].z * wv[2].x + xv[i].w * wv[3].x;
            acc[i].y += xv[i].x * wv[0].y + xv[i].y * wv[1].y
                      + xv[i].z * wv[2].y + xv[i].w * wv[3].y;
            acc[i].z += xv[i].x * wv[0].z + xv[i].y * wv[1].z
                      + xv[i].z * wv[2].z + xv[i].w * wv[3].z;
            acc[i].w += xv[i].x * wv[0].w + xv[i].y * wv[1].w
                      + xv[i].z * wv[2].w + xv[i].w * wv[3].w;
        }
    }
    float4 bv = make_float4(0.f, 0.f, 0.f, 0.f);
    if (BIAS) bv = *(const float4*)&bias[tc];
#pragma unroll
    for (int i = 0; i < 8; ++i) {
        int r = row0 + rbase + 16 * i;
        if (r < n) {
            float s = PRE ? dinv[r] : 1.f;
            float4 o;
            o.x = (acc[i].x + bv.x) * s;
            o.y = (acc[i].y + bv.y) * s;
            o.z = (acc[i].z + bv.z) * s;
            o.w = (acc[i].w + bv.w) * s;
            *(float4*)&H[(size_t)r * 64 + tc] = o;
        }
    }
}

// Aggregation: wave = 1 node; 4 groups of 16 lanes; group g walks edges
// e0+g, e0+g+4, ... loading prescaled rows as float4; 8 rows in flight/wave.
// out[n] = relu( dinv[n]*(sum_e Hs[src] + Hs[n]) + b )
__global__ __launch_bounds__(256) void k_agg(const float4* __restrict__ Hs4,
                                             const int* __restrict__ noffs,
                                             const int* __restrict__ csr_src,
                                             const float* __restrict__ dinv,
                                             const float4* __restrict__ b4,
                                             float4* __restrict__ out4) {
    int node = blockIdx.x * 4 + (threadIdx.x >> 6);
    if (node >= NN) return;
    int lane = threadIdx.x & 63;
    int g = lane >> 4;          // edge group 0..3
    int q = lane & 15;          // float4 chunk within the 64-feature row
    float dv = dinv[node];

    float4 acc = make_float4(0.f, 0.f, 0.f, 0.f);
    if (g == 0) acc = Hs4[(size_t)node * 16 + q];   // self-loop (prescaled)
    int e0 = noffs[node], e1 = noffs[node + 1];
    int e = e0 + g;
    for (; e + 4 < e1; e += 8) {
        int s0 = csr_src[e], s1 = csr_src[e + 4];
        float4 h0 = Hs4[(size_t)s0 * 16 + q];
        float4 h1 = Hs4[(size_t)s1 * 16 + q];
        acc.x += h0.x + h1.x; acc.y += h0.y + h1.y;
        acc.z += h0.z + h1.z; acc.w += h0.w + h1.w;
    }
    if (e < e1) {
        int s = csr_src[e];
        float4 h = Hs4[(size_t)s * 16 + q];
        acc.x += h.x; acc.y += h.y; acc.z += h.z; acc.w += h.w;
    }
#pragma unroll
    for (int off = 16; off < 64; off <<= 1) {
        acc.x += __shfl_xor(acc.x, off, 64);
        acc.y += __shfl_xor(acc.y, off, 64);
        acc.z += __shfl_xor(acc.z, off, 64);
        acc.w += __shfl_xor(acc.w, off, 64);
    }
    if (g == 0) {
        float4 bv = b4[q];
        float4 r;
        r.x = fmaxf(acc.x * dv + bv.x, 0.f);
        r.y = fmaxf(acc.y * dv + bv.y, 0.f);
        r.z = fmaxf(acc.z * dv + bv.z, 0.f);
        r.w = fmaxf(acc.w * dv + bv.w, 0.f);
        out4[(size_t)node * 16 + q] = r;
    }
}

extern "C" void kernel_launch(void* const* d_in, const int* in_sizes, int n_in,
                              void* d_out, int out_size, void* d_ws, size_t ws_size,
                              hipStream_t stream) {
    const float* x  = (const float*)d_in[0];
    const void*  ei = d_in[1];               // edge_index, dtype detected on device
    const float* W0 = (const float*)d_in[3];
    const float* b0 = (const float*)d_in[4];
    const float* W1 = (const float*)d_in[5];
    const float* b1 = (const float*)d_in[6];
    const float* W2 = (const float*)d_in[7];
    const float* b2 = (const float*)d_in[8];
    const float* Wl = (const float*)d_in[9];
    const float* bl = (const float*)d_in[10];

    char* ws = (char*)d_ws;
    int*      flag    = (int*)(ws);
    int*      bcnt    = (int*)(ws + 256);
    int*      offs    = (int*)(ws + 4352);        // 783 ints
    int*      curs    = (int*)(ws + 8448);        // 782 ints
    float*    dinv    = (float*)(ws + 12544);     // 400000 B
    int*      noffs   = (int*)(ws + 412672);      // 100001 ints
    int*      csr_src = (int*)(ws + 812800);      // 3.2 MB

    float* out0 = (float*)d_out;             // first output (layer-3 relu)
    float* out1 = out0 + (size_t)NN * HD;    // second output; Hs scratch
    unsigned* ebuf = (unsigned*)out1;        // bucket-major edges; dies before GEMM0

    int gG = (NN + 127) / 128;               // 782 gemm blocks
    int gA = (NN + 3) / 4;                   // 25000 agg blocks

    // ---- preprocessing: bucket bin + in-bucket counting sort -> CSR ----
    k_init<<<1, 1024, 0, stream>>>(bcnt, flag);
    k_detect<<<1, 1024, 0, stream>>>(ei, flag);
    k_pass0<<<128, 256, 0, stream>>>(ei, flag, bcnt);
    k_scan1<<<1, 256, 0, stream>>>(bcnt, offs, curs);
    k_passA<<<PA_NB, 256, 0, stream>>>(ei, flag, curs, ebuf);
    k_passB<<<NBUCK, 256, 0, stream>>>(ebuf, offs, noffs, csr_src, dinv);

    // ---- layer 0 ----
    k_gemm<false, true><<<gG, 256, 0, stream>>>(x, W0, nullptr, dinv, out1, NN);
    k_agg<<<gA, 256, 0, stream>>>((const float4*)out1, noffs, csr_src, dinv,
                                  (const float4*)b0, (float4*)out0);
    // ---- layer 1 ----
    k_gemm<false, true><<<gG, 256, 0, stream>>>(out0, W1, nullptr, dinv, out1, NN);
    k_agg<<<gA, 256, 0, stream>>>((const float4*)out1, noffs, csr_src, dinv,
                                  (const float4*)b1, (float4*)out0);
    // ---- layer 2 ----
    k_gemm<false, true><<<gG, 256, 0, stream>>>(out0, W2, nullptr, dinv, out1, NN);
    k_agg<<<gA, 256, 0, stream>>>((const float4*)out1, noffs, csr_src, dinv,
                                  (const float4*)b2, (float4*)out0);
    // ---- final linear ----
    k_gemm<true, false><<<gG, 256, 0, stream>>>(out0, Wl, bl, nullptr, out1, NN);
}

// Round 8
// 347.173 us; speedup vs baseline: 1.6424x; 1.0073x over previous
//
#include <hip/hip_runtime.h>

#define NN 100000
#define NE 800000
#define HD 64
#define BK 128                            // nodes per bucket
#define NBUCK ((NN + BK - 1) / BK)        // 782
#define PA_EPT 16                         // edges per thread in passA
#define PA_NB ((NE + 256 * PA_EPT - 1) / (256 * PA_EPT))   // 196
#define LDW 68                            // padded leading dim: 68 f = 272 B = 17*16 B

__device__ __forceinline__ int load_idx(const void* ei, int i, bool is32) {
    if (is32) return ((const int*)ei)[i];
    return (int)(((const long long*)ei)[i]);
}

__device__ __forceinline__ unsigned short f2bf(float f) {   // round-to-nearest
    unsigned u = __float_as_uint(f);
    return (unsigned short)((u + 0x7FFFu + ((u >> 16) & 1u)) >> 16);
}
__device__ __forceinline__ float bf2f(unsigned short h) {
    return __uint_as_float((unsigned)h << 16);
}

// zero flag + bucket counters
__global__ void k_init(int* bcnt, int* flag) {
    int t = threadIdx.x;
    if (t < NBUCK) bcnt[t] = 0;
    if (t == NBUCK) *flag = 0;
}

// detect int32 vs int64: one block checks the first 4096 int64 slots.
__global__ void k_detect(const void* ei, int* flag) {
    __shared__ int bad;
    if (threadIdx.x == 0) bad = 0;
    __syncthreads();
    const long long* p = (const long long*)ei;
    for (int i = threadIdx.x; i < 4096; i += 1024) {
        long long v = p[i];
        if (v < 0 || v >= (long long)NN) bad = 1;
    }
    __syncthreads();
    if (threadIdx.x == 0 && bad) *flag = 1;
}

// global bucket histogram via per-block LDS histograms
__global__ __launch_bounds__(256) void k_pass0(const void* ei, const int* flag,
                                               int* bcnt) {
    __shared__ int h[NBUCK];
    for (int i = threadIdx.x; i < NBUCK; i += 256) h[i] = 0;
    __syncthreads();
    bool is32 = (*flag != 0);
    int stride = gridDim.x * 256;
    for (int e = blockIdx.x * 256 + threadIdx.x; e < NE; e += stride) {
        int dst = load_idx(ei, NE + e, is32);
        atomicAdd(&h[dst >> 7], 1);
    }
    __syncthreads();
    for (int i = threadIdx.x; i < NBUCK; i += 256) {
        int v = h[i];
        if (v) atomicAdd(&bcnt[i], v);
    }
}

// scan 782 bucket counts -> offs[0..NBUCK], curs[b]=offs[b]
__global__ __launch_bounds__(256) void k_scan1(const int* __restrict__ bcnt,
                                               int* __restrict__ offs,
                                               int* __restrict__ curs) {
    __shared__ int sc[256];
    int t = threadIdx.x;
    int v[4], s = 0;
#pragma unroll
    for (int i = 0; i < 4; ++i) {
        int b = t * 4 + i;
        v[i] = (b < NBUCK) ? bcnt[b] : 0;
        s += v[i];
    }
    sc[t] = s;
    __syncthreads();
    for (int off = 1; off < 256; off <<= 1) {
        int add = (t >= off) ? sc[t - off] : 0;
        __syncthreads();
        sc[t] += add;
        __syncthreads();
    }
    int run = sc[t] - s;   // exclusive prefix
#pragma unroll
    for (int i = 0; i < 4; ++i) {
        int b = t * 4 + i;
        if (b < NBUCK) { offs[b] = run; curs[b] = run; }
        run += v[i];
    }
    if (t == 255) offs[NBUCK] = sc[255];
}

// bin edges into bucket-major ebuf; packed word = src | (dst&127)<<17
__global__ __launch_bounds__(256) void k_passA(const void* ei, const int* flag,
                                               int* curs, unsigned* ebuf) {
    __shared__ int h[NBUCK];
    __shared__ int base[NBUCK];
    for (int i = threadIdx.x; i < NBUCK; i += 256) h[i] = 0;
    __syncthreads();
    bool is32 = (*flag != 0);
    int e0 = blockIdx.x * (256 * PA_EPT);
    int src[PA_EPT], dst[PA_EPT];
#pragma unroll
    for (int i = 0; i < PA_EPT; ++i) {
        int e = e0 + i * 256 + threadIdx.x;
        if (e < NE) {
            src[i] = load_idx(ei, e, is32);
            dst[i] = load_idx(ei, NE + e, is32);
            atomicAdd(&h[dst[i] >> 7], 1);
        } else dst[i] = -1;
    }
    __syncthreads();
    for (int i = threadIdx.x; i < NBUCK; i += 256) {
        int v = h[i];
        base[i] = v ? atomicAdd(&curs[i], v) : 0;
        h[i] = 0;                      // reuse as local rank counter
    }
    __syncthreads();
#pragma unroll
    for (int i = 0; i < PA_EPT; ++i) {
        if (dst[i] >= 0) {
            int b = dst[i] >> 7;
            int p = base[b] + atomicAdd(&h[b], 1);
            ebuf[p] = (unsigned)src[i] | ((unsigned)(dst[i] & 127) << 17);
        }
    }
}

// per-bucket counting sort -> per-node CSR (noffs, csr_src) + dinv.
__global__ __launch_bounds__(256) void k_passB(const unsigned* __restrict__ ebuf,
                                               const int* __restrict__ offs,
                                               int* __restrict__ noffs,
                                               int* __restrict__ csr_src,
                                               float* __restrict__ dinv) {
    __shared__ int cnt[BK];
    __shared__ int sc[BK];
    __shared__ int nbase[BK];
    __shared__ int rank[BK];
    int bk = blockIdx.x;
    int t = threadIdx.x;
    if (t < BK) { cnt[t] = 0; rank[t] = 0; }
    __syncthreads();
    int rs = offs[bk], re = offs[bk + 1];
    for (int i = rs + t; i < re; i += 256)
        atomicAdd(&cnt[ebuf[i] >> 17], 1);
    __syncthreads();
    if (t < BK) sc[t] = cnt[t];
    __syncthreads();
    for (int off = 1; off < BK; off <<= 1) {       // inclusive scan of cnt
        int v = 0;
        if (t < BK && t >= off) v = sc[t - off];
        __syncthreads();
        if (t < BK) sc[t] += v;
        __syncthreads();
    }
    if (t < BK) {
        int node = bk * BK + t;
        int nb = rs + sc[t] - cnt[t];              // exclusive prefix
        nbase[t] = nb;
        if (node < NN) {
            noffs[node] = nb;
            dinv[node] = rsqrtf((float)(cnt[t] + 1));
        }
    }
    if (bk == NBUCK - 1 && t == 0) noffs[NN] = re;
    __syncthreads();
    for (int i = rs + t; i < re; i += 256) {
        unsigned w = ebuf[i];
        int dl = w >> 17;
        int p = nbase[dl] + atomicAdd(&rank[dl], 1);
        csr_src[p] = (int)(w & 0x1FFFFu);
    }
}

// H[n x 64] = X[n x 64] @ W[64 x 64]; 128 rows/block; thread = 8 rows
// (strided by 16) x 4 cols. unroll 1 + launch_bounds(256,4): VGPR<=128
// (R6 lesson: full unroll hit 256-VGPR cap, occupancy collapse).
// BF16OUT: write prescaled rows as bf16 (halves gather traffic in k_agg).
template <bool BIAS, bool PRE, bool BF16OUT>
__global__ __launch_bounds__(256, 4) void k_gemm(const float* __restrict__ X,
                                                 const float* __restrict__ W,
                                                 const float* __restrict__ bias,
                                                 const float* __restrict__ dinv,
                                                 void* __restrict__ Hout, int n) {
    __shared__ float Ws[64 * LDW];     // 17.4 KB
    __shared__ float Xs[128 * LDW];    // 34.8 KB
    int t = threadIdx.x;
    int row0 = blockIdx.x * 128;
    const float4* X4 = (const float4*)X;
    for (int i = t; i < 64 * 16; i += 256) {       // W: 1024 float4
        float4 v = ((const float4*)W)[i];
        *(float4*)&Ws[(i >> 4) * LDW + (i & 15) * 4] = v;
    }
    for (int i = t; i < 128 * 16; i += 256) {      // X tile: 2048 float4
        int r = row0 + (i >> 4);
        float4 v = (r < n) ? X4[(size_t)r * 16 + (i & 15)]
                           : make_float4(0.f, 0.f, 0.f, 0.f);
        *(float4*)&Xs[(i >> 4) * LDW + (i & 15) * 4] = v;
    }
    __syncthreads();
    int tc = (t & 15) * 4;       // 4 output cols
    int rbase = t >> 4;          // rows rbase + 16*i, i=0..7
    float4 acc[8] = {};
#pragma unroll 1
    for (int k = 0; k < 64; k += 4) {
        float4 wv[4], xv[8];
#pragma unroll
        for (int kk = 0; kk < 4; ++kk)
            wv[kk] = *(const float4*)&Ws[(k + kk) * LDW + tc];
#pragma unroll
        for (int i = 0; i < 8; ++i)
            xv[i] = *(const float4*)&Xs[(rbase + 16 * i) * LDW + k];
#pragma unroll
        for (int i = 0; i < 8; ++i) {
            acc[i].x += xv[i].x * wv[0].x + xv[i].y * wv[1].x
                      + xv[i].z * wv[2].x + xv[i].w * wv[3].x;
            acc[i].y += xv[i].x * wv[0].y + xv[i].y * wv[1].y
                      + xv[i].z * wv[2].y + xv[i].w * wv[3].y;
            acc[i].z += xv[i].x * wv[0].z + xv[i].y * wv[1].z
                      + xv[i].z * wv[2].z + xv[i].w * wv[3].z;
            acc[i].w += xv[i].x * wv[0].w + xv[i].y * wv[1].w
                      + xv[i].z * wv[2].w + xv[i].w * wv[3].w;
        }
    }
    float4 bv = make_float4(0.f, 0.f, 0.f, 0.f);
    if (BIAS) bv = *(const float4*)&bias[tc];
#pragma unroll
    for (int i = 0; i < 8; ++i) {
        int r = row0 + rbase + 16 * i;
        if (r < n) {
            float s = PRE ? dinv[r] : 1.f;
            float4 o;
            o.x = (acc[i].x + bv.x) * s;
            o.y = (acc[i].y + bv.y) * s;
            o.z = (acc[i].z + bv.z) * s;
            o.w = (acc[i].w + bv.w) * s;
            if (BF16OUT) {
                ushort4 p;
                p.x = f2bf(o.x); p.y = f2bf(o.y); p.z = f2bf(o.z); p.w = f2bf(o.w);
                ((ushort4*)Hout)[(size_t)r * 16 + (t & 15)] = p;
            } else {
                ((float4*)Hout)[(size_t)r * 16 + (t & 15)] = o;
            }
        }
    }
}

// Aggregation over bf16 prescaled rows: wave = 1 node; 4 groups of 16 lanes;
// group g walks edges e0+g, e0+g+4, ... loading 128 B rows as ushort4
// (16 lanes x 8 B); fp32 accumulate; shfl reduce; lanes 0-15 write float4.
// out[n] = relu( dinv[n]*(sum_e Hs[src] + Hs[n]) + b )
__global__ __launch_bounds__(256) void k_agg(const ushort4* __restrict__ Hb,
                                             const int* __restrict__ noffs,
                                             const int* __restrict__ csr_src,
                                             const float* __restrict__ dinv,
                                             const float4* __restrict__ b4,
                                             float4* __restrict__ out4) {
    int node = blockIdx.x * 4 + (threadIdx.x >> 6);
    if (node >= NN) return;
    int lane = threadIdx.x & 63;
    int g = lane >> 4;          // edge group 0..3
    int q = lane & 15;          // ushort4 chunk within the 64-feature row
    float dv = dinv[node];

    float4 acc = make_float4(0.f, 0.f, 0.f, 0.f);
    if (g == 0) {               // self-loop (prescaled)
        ushort4 h = Hb[(size_t)node * 16 + q];
        acc.x = bf2f(h.x); acc.y = bf2f(h.y); acc.z = bf2f(h.z); acc.w = bf2f(h.w);
    }
    int e0 = noffs[node], e1 = noffs[node + 1];
    int e = e0 + g;
    for (; e + 4 < e1; e += 8) {
        int s0 = csr_src[e], s1 = csr_src[e + 4];
        ushort4 h0 = Hb[(size_t)s0 * 16 + q];
        ushort4 h1 = Hb[(size_t)s1 * 16 + q];
        acc.x += bf2f(h0.x) + bf2f(h1.x);
        acc.y += bf2f(h0.y) + bf2f(h1.y);
        acc.z += bf2f(h0.z) + bf2f(h1.z);
        acc.w += bf2f(h0.w) + bf2f(h1.w);
    }
    if (e < e1) {
        int s = csr_src[e];
        ushort4 h = Hb[(size_t)s * 16 + q];
        acc.x += bf2f(h.x); acc.y += bf2f(h.y);
        acc.z += bf2f(h.z); acc.w += bf2f(h.w);
    }
#pragma unroll
    for (int off = 16; off < 64; off <<= 1) {
        acc.x += __shfl_xor(acc.x, off, 64);
        acc.y += __shfl_xor(acc.y, off, 64);
        acc.z += __shfl_xor(acc.z, off, 64);
        acc.w += __shfl_xor(acc.w, off, 64);
    }
    if (g == 0) {
        float4 bv = b4[q];
        float4 r;
        r.x = fmaxf(acc.x * dv + bv.x, 0.f);
        r.y = fmaxf(acc.y * dv + bv.y, 0.f);
        r.z = fmaxf(acc.z * dv + bv.z, 0.f);
        r.w = fmaxf(acc.w * dv + bv.w, 0.f);
        out4[(size_t)node * 16 + q] = r;
    }
}

extern "C" void kernel_launch(void* const* d_in, const int* in_sizes, int n_in,
                              void* d_out, int out_size, void* d_ws, size_t ws_size,
                              hipStream_t stream) {
    const float* x  = (const float*)d_in[0];
    const void*  ei = d_in[1];               // edge_index, dtype detected on device
    const float* W0 = (const float*)d_in[3];
    const float* b0 = (const float*)d_in[4];
    const float* W1 = (const float*)d_in[5];
    const float* b1 = (const float*)d_in[6];
    const float* W2 = (const float*)d_in[7];
    const float* b2 = (const float*)d_in[8];
    const float* Wl = (const float*)d_in[9];
    const float* bl = (const float*)d_in[10];

    char* ws = (char*)d_ws;
    int*      flag    = (int*)(ws);
    int*      bcnt    = (int*)(ws + 256);
    int*      offs    = (int*)(ws + 4352);        // 783 ints
    int*      curs    = (int*)(ws + 8448);        // 782 ints
    float*    dinv    = (float*)(ws + 12544);     // 400000 B
    int*      noffs   = (int*)(ws + 412672);      // 100001 ints
    int*      csr_src = (int*)(ws + 812800);      // 3.2 MB

    float* out0 = (float*)d_out;             // first output (layer-3 relu)
    float* out1 = out0 + (size_t)NN * HD;    // second output
    unsigned* ebuf = (unsigned*)out1;        // bucket-major edges; dies pre-GEMM0
    void* Hb = (void*)out1;                  // bf16 Hs (12.8 MB); dies pre-final-GEMM

    int gG = (NN + 127) / 128;               // 782 gemm blocks
    int gA = (NN + 3) / 4;                   // 25000 agg blocks

    // ---- preprocessing: bucket bin + in-bucket counting sort -> CSR ----
    k_init<<<1, 1024, 0, stream>>>(bcnt, flag);
    k_detect<<<1, 1024, 0, stream>>>(ei, flag);
    k_pass0<<<128, 256, 0, stream>>>(ei, flag, bcnt);
    k_scan1<<<1, 256, 0, stream>>>(bcnt, offs, curs);
    k_passA<<<PA_NB, 256, 0, stream>>>(ei, flag, curs, ebuf);
    k_passB<<<NBUCK, 256, 0, stream>>>(ebuf, offs, noffs, csr_src, dinv);

    // ---- layer 0 ----
    k_gemm<false, true, true><<<gG, 256, 0, stream>>>(x, W0, nullptr, dinv, Hb, NN);
    k_agg<<<gA, 256, 0, stream>>>((const ushort4*)Hb, noffs, csr_src, dinv,
                                  (const float4*)b0, (float4*)out0);
    // ---- layer 1 ----
    k_gemm<false, true, true><<<gG, 256, 0, stream>>>(out0, W1, nullptr, dinv, Hb, NN);
    k_agg<<<gA, 256, 0, stream>>>((const ushort4*)Hb, noffs, csr_src, dinv,
                                  (const float4*)b1, (float4*)out0);
    // ---- layer 2 ----
    k_gemm<false, true, true><<<gG, 256, 0, stream>>>(out0, W2, nullptr, dinv, Hb, NN);
    k_agg<<<gA, 256, 0, stream>>>((const ushort4*)Hb, noffs, csr_src, dinv,
                                  (const float4*)b2, (float4*)out0);
    // ---- final linear (fp32 out) ----
    k_gemm<true, false, false><<<gG, 256, 0, stream>>>(out0, Wl, bl, nullptr,
                                                       (void*)out1, NN);
}

// Round 9
// 308.495 us; speedup vs baseline: 1.8483x; 1.1254x over previous
//
#include <hip/hip_runtime.h>

#define NN 100000
#define NE 800000
#define HD 64
#define BK 128                            // nodes per bucket
#define NBUCK ((NN + BK - 1) / BK)        // 782
#define PA_EPT 16                         // edges per thread in passA
#define PA_NB ((NE + 256 * PA_EPT - 1) / (256 * PA_EPT))   // 196
#define LDW 68                            // padded leading dim: 68 f = 272 B = 17*16 B

__device__ __forceinline__ int load_idx(const void* ei, int i, bool is32) {
    if (is32) return ((const int*)ei)[i];
    return (int)(((const long long*)ei)[i]);
}

__device__ __forceinline__ unsigned short f2bf(float f) {   // round-to-nearest
    unsigned u = __float_as_uint(f);
    return (unsigned short)((u + 0x7FFFu + ((u >> 16) & 1u)) >> 16);
}

// expand uint4 (8 packed bf16, feature order) and accumulate into 2 float4s
__device__ __forceinline__ void bfacc(const uint4& u, float4& a, float4& b) {
    a.x += __uint_as_float(u.x << 16);
    a.y += __uint_as_float(u.x & 0xFFFF0000u);
    a.z += __uint_as_float(u.y << 16);
    a.w += __uint_as_float(u.y & 0xFFFF0000u);
    b.x += __uint_as_float(u.z << 16);
    b.y += __uint_as_float(u.z & 0xFFFF0000u);
    b.z += __uint_as_float(u.w << 16);
    b.w += __uint_as_float(u.w & 0xFFFF0000u);
}

// zero bucket counters + flag, then dtype-detect (int32 vs int64) in one launch.
__global__ void k_initdet(const void* ei, int* bcnt, int* flag) {
    __shared__ int bad;
    int t = threadIdx.x;
    if (t == 0) bad = 0;
    if (t < NBUCK) bcnt[t] = 0;
    __syncthreads();
    const long long* p = (const long long*)ei;
    for (int i = t; i < 4096; i += 1024) {
        long long v = p[i];
        if (v < 0 || v >= (long long)NN) bad = 1;
    }
    __syncthreads();
    if (t == 0) *flag = bad ? 1 : 0;
}

// global bucket histogram via per-block LDS histograms
__global__ __launch_bounds__(256) void k_pass0(const void* ei, const int* flag,
                                               int* bcnt) {
    __shared__ int h[NBUCK];
    for (int i = threadIdx.x; i < NBUCK; i += 256) h[i] = 0;
    __syncthreads();
    bool is32 = (*flag != 0);
    int stride = gridDim.x * 256;
    for (int e = blockIdx.x * 256 + threadIdx.x; e < NE; e += stride) {
        int dst = load_idx(ei, NE + e, is32);
        atomicAdd(&h[dst >> 7], 1);
    }
    __syncthreads();
    for (int i = threadIdx.x; i < NBUCK; i += 256) {
        int v = h[i];
        if (v) atomicAdd(&bcnt[i], v);
    }
}

// scan 782 bucket counts -> offs[0..NBUCK], curs[b]=offs[b]
__global__ __launch_bounds__(256) void k_scan1(const int* __restrict__ bcnt,
                                               int* __restrict__ offs,
                                               int* __restrict__ curs) {
    __shared__ int sc[256];
    int t = threadIdx.x;
    int v[4], s = 0;
#pragma unroll
    for (int i = 0; i < 4; ++i) {
        int b = t * 4 + i;
        v[i] = (b < NBUCK) ? bcnt[b] : 0;
        s += v[i];
    }
    sc[t] = s;
    __syncthreads();
    for (int off = 1; off < 256; off <<= 1) {
        int add = (t >= off) ? sc[t - off] : 0;
        __syncthreads();
        sc[t] += add;
        __syncthreads();
    }
    int run = sc[t] - s;   // exclusive prefix
#pragma unroll
    for (int i = 0; i < 4; ++i) {
        int b = t * 4 + i;
        if (b < NBUCK) { offs[b] = run; curs[b] = run; }
        run += v[i];
    }
    if (t == 255) offs[NBUCK] = sc[255];
}

// bin edges into bucket-major ebuf; packed word = src | (dst&127)<<17
__global__ __launch_bounds__(256) void k_passA(const void* ei, const int* flag,
                                               int* curs, unsigned* ebuf) {
    __shared__ int h[NBUCK];
    __shared__ int base[NBUCK];
    for (int i = threadIdx.x; i < NBUCK; i += 256) h[i] = 0;
    __syncthreads();
    bool is32 = (*flag != 0);
    int e0 = blockIdx.x * (256 * PA_EPT);
    int src[PA_EPT], dst[PA_EPT];
#pragma unroll
    for (int i = 0; i < PA_EPT; ++i) {
        int e = e0 + i * 256 + threadIdx.x;
        if (e < NE) {
            src[i] = load_idx(ei, e, is32);
            dst[i] = load_idx(ei, NE + e, is32);
            atomicAdd(&h[dst[i] >> 7], 1);
        } else dst[i] = -1;
    }
    __syncthreads();
    for (int i = threadIdx.x; i < NBUCK; i += 256) {
        int v = h[i];
        base[i] = v ? atomicAdd(&curs[i], v) : 0;
        h[i] = 0;                      // reuse as local rank counter
    }
    __syncthreads();
#pragma unroll
    for (int i = 0; i < PA_EPT; ++i) {
        if (dst[i] >= 0) {
            int b = dst[i] >> 7;
            int p = base[b] + atomicAdd(&h[b], 1);
            ebuf[p] = (unsigned)src[i] | ((unsigned)(dst[i] & 127) << 17);
        }
    }
}

// per-bucket counting sort -> per-node CSR (noffs, csr_src) + dinv.
__global__ __launch_bounds__(256) void k_passB(const unsigned* __restrict__ ebuf,
                                               const int* __restrict__ offs,
                                               int* __restrict__ noffs,
                                               int* __restrict__ csr_src,
                                               float* __restrict__ dinv) {
    __shared__ int cnt[BK];
    __shared__ int sc[BK];
    __shared__ int nbase[BK];
    __shared__ int rank[BK];
    int bk = blockIdx.x;
    int t = threadIdx.x;
    if (t < BK) { cnt[t] = 0; rank[t] = 0; }
    __syncthreads();
    int rs = offs[bk], re = offs[bk + 1];
    for (int i = rs + t; i < re; i += 256)
        atomicAdd(&cnt[ebuf[i] >> 17], 1);
    __syncthreads();
    if (t < BK) sc[t] = cnt[t];
    __syncthreads();
    for (int off = 1; off < BK; off <<= 1) {       // inclusive scan of cnt
        int v = 0;
        if (t < BK && t >= off) v = sc[t - off];
        __syncthreads();
        if (t < BK) sc[t] += v;
        __syncthreads();
    }
    if (t < BK) {
        int node = bk * BK + t;
        int nb = rs + sc[t] - cnt[t];              // exclusive prefix
        nbase[t] = nb;
        if (node < NN) {
            noffs[node] = nb;
            dinv[node] = rsqrtf((float)(cnt[t] + 1));
        }
    }
    if (bk == NBUCK - 1 && t == 0) noffs[NN] = re;
    __syncthreads();
    for (int i = rs + t; i < re; i += 256) {
        unsigned w = ebuf[i];
        int dl = w >> 17;
        int p = nbase[dl] + atomicAdd(&rank[dl], 1);
        csr_src[p] = (int)(w & 0x1FFFFu);
    }
}

// H[n x 64] = X[n x 64] @ W[64 x 64]; 128 rows/block; thread = 8 rows
// (strided by 16) x 4 cols. unroll 1 + launch_bounds(256,4): VGPR<=128
// (R6 lesson: full unroll hit 256-VGPR cap, occupancy collapse).
// BF16OUT: write prescaled rows as bf16 (halves gather traffic in k_agg).
template <bool BIAS, bool PRE, bool BF16OUT>
__global__ __launch_bounds__(256, 4) void k_gemm(const float* __restrict__ X,
                                                 const float* __restrict__ W,
                                                 const float* __restrict__ bias,
                                                 const float* __restrict__ dinv,
                                                 void* __restrict__ Hout, int n) {
    __shared__ float Ws[64 * LDW];     // 17.4 KB
    __shared__ float Xs[128 * LDW];    // 34.8 KB
    int t = threadIdx.x;
    int row0 = blockIdx.x * 128;
    const float4* X4 = (const float4*)X;
    for (int i = t; i < 64 * 16; i += 256) {       // W: 1024 float4
        float4 v = ((const float4*)W)[i];
        *(float4*)&Ws[(i >> 4) * LDW + (i & 15) * 4] = v;
    }
    for (int i = t; i < 128 * 16; i += 256) {      // X tile: 2048 float4
        int r = row0 + (i >> 4);
        float4 v = (r < n) ? X4[(size_t)r * 16 + (i & 15)]
                           : make_float4(0.f, 0.f, 0.f, 0.f);
        *(float4*)&Xs[(i >> 4) * LDW + (i & 15) * 4] = v;
    }
    __syncthreads();
    int tc = (t & 15) * 4;       // 4 output cols
    int rbase = t >> 4;          // rows rbase + 16*i, i=0..7
    float4 acc[8] = {};
#pragma unroll 1
    for (int k = 0; k < 64; k += 4) {
        float4 wv[4], xv[8];
#pragma unroll
        for (int kk = 0; kk < 4; ++kk)
            wv[kk] = *(const float4*)&Ws[(k + kk) * LDW + tc];
#pragma unroll
        for (int i = 0; i < 8; ++i)
            xv[i] = *(const float4*)&Xs[(rbase + 16 * i) * LDW + k];
#pragma unroll
        for (int i = 0; i < 8; ++i) {
            acc[i].x += xv[i].x * wv[0].x + xv[i].y * wv[1].x
                      + xv[i].z * wv[2].x + xv[i].w * wv[3].x;
            acc[i].y += xv[i].x * wv[0].y + xv[i].y * wv[1].y
                      + xv[i].z * wv[2].y + xv[i].w * wv[3].y;
            acc[i].z += xv[i].x * wv[0].z + xv[i].y * wv[1].z
                      + xv[i].z * wv[2].z + xv[i].w * wv[3].z;
            acc[i].w += xv[i].x * wv[0].w + xv[i].y * wv[1].w
                      + xv[i].z * wv[2].w + xv[i].w * wv[3].w;
        }
    }
    float4 bv = make_float4(0.f, 0.f, 0.f, 0.f);
    if (BIAS) bv = *(const float4*)&bias[tc];
#pragma unroll
    for (int i = 0; i < 8; ++i) {
        int r = row0 + rbase + 16 * i;
        if (r < n) {
            float s = PRE ? dinv[r] : 1.f;
            float4 o;
            o.x = (acc[i].x + bv.x) * s;
            o.y = (acc[i].y + bv.y) * s;
            o.z = (acc[i].z + bv.z) * s;
            o.w = (acc[i].w + bv.w) * s;
            if (BF16OUT) {
                ushort4 p;
                p.x = f2bf(o.x); p.y = f2bf(o.y); p.z = f2bf(o.z); p.w = f2bf(o.w);
                ((ushort4*)Hout)[(size_t)r * 16 + (t & 15)] = p;
            } else {
                ((float4*)Hout)[(size_t)r * 16 + (t & 15)] = o;
            }
        }
    }
}

// Aggregation over bf16 rows, 2 nodes per wave for 2x memory-level parallelism:
// half-wave (32 lanes) = 1 node = 4 clusters of 8 lanes; cluster c loads full
// 128 B rows as uint4 (8 lanes x 16 B) walking edges e0+c, e0+c+4, ... with
// 2-deep unroll -> 16 independent row-gathers in flight per wave (R8 had 8;
// R8's byte-halving didn't help -> latency-bound, so raise outstanding count).
// out[n] = relu( dinv[n]*(sum_e Hs[src] + Hs[n]) + b )
__global__ __launch_bounds__(256) void k_agg(const uint4* __restrict__ Hb,
                                             const int* __restrict__ noffs,
                                             const int* __restrict__ csr_src,
                                             const float* __restrict__ dinv,
                                             const float4* __restrict__ b4,
                                             float4* __restrict__ out4) {
    int wave = threadIdx.x >> 6;            // 0..3
    int lane = threadIdx.x & 63;
    int half = lane >> 5;                   // which of the wave's 2 nodes
    int hl   = lane & 31;
    int c    = hl >> 3;                     // cluster 0..3
    int q    = hl & 7;                      // uint4 chunk 0..7 (features 8q..8q+7)
    int node = blockIdx.x * 8 + wave * 2 + half;
    if (node >= NN) return;
    float dv = dinv[node];

    float4 alo = make_float4(0.f, 0.f, 0.f, 0.f);
    float4 ahi = make_float4(0.f, 0.f, 0.f, 0.f);
    if (c == 0) {                           // self-loop (prescaled)
        uint4 u = Hb[(size_t)node * 8 + q];
        bfacc(u, alo, ahi);
    }
    int e0 = noffs[node], e1 = noffs[node + 1];
    int e = e0 + c;
    for (; e + 4 < e1; e += 8) {
        uint4 u0 = Hb[(size_t)csr_src[e] * 8 + q];
        uint4 u1 = Hb[(size_t)csr_src[e + 4] * 8 + q];
        bfacc(u0, alo, ahi);
        bfacc(u1, alo, ahi);
    }
    if (e < e1) {
        uint4 u = Hb[(size_t)csr_src[e] * 8 + q];
        bfacc(u, alo, ahi);
    }
    // reduce the 4 clusters within each 32-lane half (offsets stay in-half)
#pragma unroll
    for (int off = 8; off < 32; off <<= 1) {
        alo.x += __shfl_xor(alo.x, off, 64);
        alo.y += __shfl_xor(alo.y, off, 64);
        alo.z += __shfl_xor(alo.z, off, 64);
        alo.w += __shfl_xor(alo.w, off, 64);
        ahi.x += __shfl_xor(ahi.x, off, 64);
        ahi.y += __shfl_xor(ahi.y, off, 64);
        ahi.z += __shfl_xor(ahi.z, off, 64);
        ahi.w += __shfl_xor(ahi.w, off, 64);
    }
    if (c == 0) {                           // lanes q=0..7 of each half write
        float4 b0v = b4[2 * q], b1v = b4[2 * q + 1];
        float4 r0, r1;
        r0.x = fmaxf(alo.x * dv + b0v.x, 0.f);
        r0.y = fmaxf(alo.y * dv + b0v.y, 0.f);
        r0.z = fmaxf(alo.z * dv + b0v.z, 0.f);
        r0.w = fmaxf(alo.w * dv + b0v.w, 0.f);
        r1.x = fmaxf(ahi.x * dv + b1v.x, 0.f);
        r1.y = fmaxf(ahi.y * dv + b1v.y, 0.f);
        r1.z = fmaxf(ahi.z * dv + b1v.z, 0.f);
        r1.w = fmaxf(ahi.w * dv + b1v.w, 0.f);
        out4[(size_t)node * 16 + 2 * q]     = r0;
        out4[(size_t)node * 16 + 2 * q + 1] = r1;
    }
}

extern "C" void kernel_launch(void* const* d_in, const int* in_sizes, int n_in,
                              void* d_out, int out_size, void* d_ws, size_t ws_size,
                              hipStream_t stream) {
    const float* x  = (const float*)d_in[0];
    const void*  ei = d_in[1];               // edge_index, dtype detected on device
    const float* W0 = (const float*)d_in[3];
    const float* b0 = (const float*)d_in[4];
    const float* W1 = (const float*)d_in[5];
    const float* b1 = (const float*)d_in[6];
    const float* W2 = (const float*)d_in[7];
    const float* b2 = (const float*)d_in[8];
    const float* Wl = (const float*)d_in[9];
    const float* bl = (const float*)d_in[10];

    char* ws = (char*)d_ws;
    int*      flag    = (int*)(ws);
    int*      bcnt    = (int*)(ws + 256);
    int*      offs    = (int*)(ws + 4352);        // 783 ints
    int*      curs    = (int*)(ws + 8448);        // 782 ints
    float*    dinv    = (float*)(ws + 12544);     // 400000 B
    int*      noffs   = (int*)(ws + 412672);      // 100001 ints
    int*      csr_src = (int*)(ws + 812800);      // 3.2 MB

    float* out0 = (float*)d_out;             // first output (layer-3 relu)
    float* out1 = out0 + (size_t)NN * HD;    // second output
    unsigned* ebuf = (unsigned*)out1;        // bucket-major edges; dies pre-GEMM0
    void* Hb = (void*)out1;                  // bf16 Hs (12.8 MB); dies pre-final-GEMM

    int gG = (NN + 127) / 128;               // 782 gemm blocks
    int gA = (NN + 7) / 8;                   // 12500 agg blocks (8 nodes each)

    // ---- preprocessing: bucket bin + in-bucket counting sort -> CSR ----
    k_initdet<<<1, 1024, 0, stream>>>(ei, bcnt, flag);
    k_pass0<<<128, 256, 0, stream>>>(ei, flag, bcnt);
    k_scan1<<<1, 256, 0, stream>>>(bcnt, offs, curs);
    k_passA<<<PA_NB, 256, 0, stream>>>(ei, flag, curs, ebuf);
    k_passB<<<NBUCK, 256, 0, stream>>>(ebuf, offs, noffs, csr_src, dinv);

    // ---- layer 0 ----
    k_gemm<false, true, true><<<gG, 256, 0, stream>>>(x, W0, nullptr, dinv, Hb, NN);
    k_agg<<<gA, 256, 0, stream>>>((const uint4*)Hb, noffs, csr_src, dinv,
                                  (const float4*)b0, (float4*)out0);
    // ---- layer 1 ----
    k_gemm<false, true, true><<<gG, 256, 0, stream>>>(out0, W1, nullptr, dinv, Hb, NN);
    k_agg<<<gA, 256, 0, stream>>>((const uint4*)Hb, noffs, csr_src, dinv,
                                  (const float4*)b1, (float4*)out0);
    // ---- layer 2 ----
    k_gemm<false, true, true><<<gG, 256, 0, stream>>>(out0, W2, nullptr, dinv, Hb, NN);
    k_agg<<<gA, 256, 0, stream>>>((const uint4*)Hb, noffs, csr_src, dinv,
                                  (const float4*)b2, (float4*)out0);
    // ---- final linear (fp32 out) ----
    k_gemm<true, false, false><<<gG, 256, 0, stream>>>(out0, Wl, bl, nullptr,
                                                       (void*)out1, NN);
}